// Round 2
// baseline (1234.976 us; speedup 1.0000x reference)
//
#include <hip/hip_runtime.h>
#include <hip/hip_bf16.h>

#define NPOS (384*384)
#define JDIM 384
#define CDIM 128
#define HNUM 4
#define DHD  32

typedef __attribute__((ext_vector_type(8))) short short8;
typedef __attribute__((ext_vector_type(4))) float floatx4;
typedef unsigned short ushort_t;

__device__ __forceinline__ float bf2f(unsigned short u){
  unsigned int x = ((unsigned int)u) << 16;
  return __builtin_bit_cast(float, x);
}
__device__ __forceinline__ unsigned short f2bf(float f){
  unsigned int u = __builtin_bit_cast(unsigned int, f);
  u = u + 0x7FFFu + ((u >> 16) & 1u);   // round-nearest-even
  return (unsigned short)(u >> 16);
}

// ---------------- LayerNorm + triangle bias ----------------
// one wave (64 lanes) per position; each lane owns 2 channels. fp32 in, bf16 xn out.
__global__ __launch_bounds__(256) void ln_tri_kernel(
    const float* __restrict__ x, const float* __restrict__ lnw,
    const float* __restrict__ lnb, const float* __restrict__ wtri,
    ushort_t* __restrict__ xn, float* __restrict__ tri)
{
  int wave = threadIdx.x >> 6, lane = threadIdx.x & 63;
  int pos = blockIdx.x * 4 + wave;
  const float2 xv = *(const float2*)(x + (size_t)pos*CDIM + lane*2);
  float x0 = xv.x, x1 = xv.y;
  float s = x0 + x1, ss = x0*x0 + x1*x1;
  #pragma unroll
  for (int o = 32; o > 0; o >>= 1){ s += __shfl_xor(s, o); ss += __shfl_xor(ss, o); }
  float mu  = s * (1.0f/128.0f);
  float var = ss * (1.0f/128.0f) - mu*mu;
  float rstd = rsqrtf(var + 1e-5f);
  float2 w2 = *(const float2*)(lnw + lane*2);
  float2 b2 = *(const float2*)(lnb + lane*2);
  float n0 = (x0 - mu)*rstd*w2.x + b2.x;
  float n1 = (x1 - mu)*rstd*w2.y + b2.y;
  ushort2 o2; o2.x = f2bf(n0); o2.y = f2bf(n1);
  *(ushort2*)(xn + (size_t)pos*CDIM + lane*2) = o2;
  // tri[pos][h] = sum_c xn[c]*w_tri[c][h]
  float4 wt0 = *(const float4*)(wtri + lane*8);      // row c0 of [128,4]
  float4 wt1 = *(const float4*)(wtri + lane*8 + 4);  // row c1
  float t0 = n0*wt0.x + n1*wt1.x;
  float t1 = n0*wt0.y + n1*wt1.y;
  float t2 = n0*wt0.z + n1*wt1.z;
  float t3 = n0*wt0.w + n1*wt1.w;
  #pragma unroll
  for (int o = 32; o > 0; o >>= 1){
    t0 += __shfl_xor(t0, o); t1 += __shfl_xor(t1, o);
    t2 += __shfl_xor(t2, o); t3 += __shfl_xor(t3, o);
  }
  if (lane == 0){
    float4 tv; tv.x=t0; tv.y=t1; tv.z=t2; tv.w=t3;
    *(float4*)(tri + (size_t)pos*4) = tv;
  }
}

// ---------------- weight transpose + cast: W[c][f] fp32 -> Wt[f][c] bf16 (5 mats) ----------------
__global__ __launch_bounds__(256) void wt_kernel(
    const float* wq, const float* wk, const float* wv,
    const float* wg, const float* wo, ushort_t* __restrict__ wt)
{
  int mat = blockIdx.x >> 6;
  int idx = ((blockIdx.x & 63) << 8) | threadIdx.x;  // output index f*128+c
  const float* src = (mat==0)?wq:(mat==1)?wk:(mat==2)?wv:(mat==3)?wg:wo;
  int f = idx >> 7, c = idx & 127;
  wt[mat*16384 + idx] = f2bf(src[c*128 + f]);
}

// ---------------- 128x128x128 MFMA GEMM tile ----------------
// A [N,128] bf16 row-major; W = B^T [128 f][128 c] bf16 row-major.
// mode: 0 none (bf16 out) | 1 *1/sqrt(32) (bf16) | 2 sigmoid(+bias) (bf16) | 3 +bias (fp32 out)
__device__ __forceinline__ void gemm_body(
    const ushort_t* __restrict__ A, const ushort_t* __restrict__ W,
    void* __restrict__ outv, const float* __restrict__ bias,
    int mode, int row0, ushort_t* As, ushort_t* Bs)
{
  int t = threadIdx.x;
  #pragma unroll
  for (int i = 0; i < 8; i++){
    int v = t + i*256;
    int row = v >> 4, c8 = v & 15;
    *(short8*)(As + row*144 + c8*8) = *(const short8*)(A + (size_t)(row0+row)*CDIM + c8*8);
    *(short8*)(Bs + row*144 + c8*8) = *(const short8*)(W + v*8);
  }
  __syncthreads();
  int w = t >> 6, lane = t & 63;
  int wm = (w & 1) * 64, wn = (w >> 1) * 64;
  int m = lane & 15, q4 = lane >> 4;
  floatx4 acc[4][4];
  #pragma unroll
  for (int mi = 0; mi < 4; mi++)
    #pragma unroll
    for (int ni = 0; ni < 4; ni++)
      acc[mi][ni] = (floatx4){0.f, 0.f, 0.f, 0.f};
  #pragma unroll
  for (int k0 = 0; k0 < 128; k0 += 32){
    int koff = k0 + q4*8;
    short8 af[4], bf[4];
    #pragma unroll
    for (int mi = 0; mi < 4; mi++) af[mi] = *(const short8*)(As + (wm + mi*16 + m)*144 + koff);
    #pragma unroll
    for (int ni = 0; ni < 4; ni++) bf[ni] = *(const short8*)(Bs + (wn + ni*16 + m)*144 + koff);
    #pragma unroll
    for (int mi = 0; mi < 4; mi++)
      #pragma unroll
      for (int ni = 0; ni < 4; ni++)
        acc[mi][ni] = __builtin_amdgcn_mfma_f32_16x16x32_bf16(af[mi], bf[ni], acc[mi][ni], 0, 0, 0);
  }
  const float scale = 0.17677669529663687f;  // 1/sqrt(32)
  #pragma unroll
  for (int mi = 0; mi < 4; mi++){
    #pragma unroll
    for (int ni = 0; ni < 4; ni++){
      int col = wn + ni*16 + m;
      float bv = (mode >= 2) ? bias[col] : 0.f;
      #pragma unroll
      for (int r = 0; r < 4; r++){
        float val = acc[mi][ni][r];
        if (mode == 1) val *= scale;
        else if (mode == 2) val = 1.f / (1.f + __expf(-(val + bv)));
        else if (mode == 3) val += bv;
        int row = wm + mi*16 + q4*4 + r;
        size_t oidx = (size_t)(row0+row)*CDIM + col;
        if (mode == 3) ((float*)outv)[oidx] = val;
        else           ((ushort_t*)outv)[oidx] = f2bf(val);
      }
    }
  }
}

__global__ __launch_bounds__(256) void proj_gemm_kernel(
    const ushort_t* __restrict__ xn, const ushort_t* __restrict__ wt,
    ushort_t* __restrict__ outb, const float* __restrict__ bg)
{
  __shared__ __align__(16) ushort_t As[128*144];
  __shared__ __align__(16) ushort_t Bs[128*144];
  int proj = blockIdx.y;                       // 0=q 1=k 2=v 3=g
  int mode = (proj == 0) ? 1 : (proj == 3) ? 2 : 0;
  gemm_body(xn, wt + proj*16384, outb + (size_t)proj*NPOS*CDIM, bg, mode,
            blockIdx.x * 128, As, Bs);
}

__global__ __launch_bounds__(256) void out_gemm_kernel(
    const ushort_t* __restrict__ og, const ushort_t* __restrict__ wt,
    float* __restrict__ out, const float* __restrict__ bo)
{
  __shared__ __align__(16) ushort_t As[128*144];
  __shared__ __align__(16) ushort_t Bs[128*144];
  gemm_body(og, wt, (void*)out, bo, 3, blockIdx.x * 128, As, Bs);
}

// ---------------- attention per (i,h); 192 threads x 2 queries ----------------
__global__ __launch_bounds__(192) void attn_kernel(
    const ushort_t* __restrict__ qb, const ushort_t* __restrict__ kb,
    const ushort_t* __restrict__ vb, const ushort_t* __restrict__ gb,
    const float* __restrict__ mask, const float* __restrict__ tri,
    ushort_t* __restrict__ og)
{
  int i = blockIdx.x, h = blockIdx.y;
  __shared__ __align__(16) ushort_t Ks[JDIM*DHD];
  __shared__ __align__(16) ushort_t Vs[JDIM*DHD];
  __shared__ float mb[JDIM];
  int t = threadIdx.x;
  size_t rbase = (size_t)i * JDIM;
  for (int idx = t; idx < JDIM*4; idx += 192){
    int j = idx >> 2, c8 = idx & 3;
    *(short8*)(Ks + j*DHD + c8*8) = *(const short8*)(kb + (rbase + j)*CDIM + h*DHD + c8*8);
    *(short8*)(Vs + j*DHD + c8*8) = *(const short8*)(vb + (rbase + j)*CDIM + h*DHD + c8*8);
  }
  for (int j = t; j < JDIM; j += 192) mb[j] = 1e9f * (mask[rbase + j] - 1.0f);
  __syncthreads();

  float qv[2][32], acc[2][32], l_[2];
  #pragma unroll
  for (int s = 0; s < 2; s++){
    int qj = t + s*192;
    #pragma unroll
    for (int c8 = 0; c8 < 4; c8++){
      short8 d = *(const short8*)(qb + (rbase + qj)*CDIM + h*DHD + c8*8);
      #pragma unroll
      for (int e = 0; e < 8; e++) qv[s][c8*8+e] = bf2f((unsigned short)d[e]);
    }
    l_[s] = 0.f;
    #pragma unroll
    for (int d = 0; d < 32; d++) acc[s][d] = 0.f;
  }

  for (int kk = 0; kk < JDIM; kk++){
    float kr[32];
    #pragma unroll
    for (int c8 = 0; c8 < 4; c8++){
      short8 dk = *(const short8*)(Ks + kk*DHD + c8*8);
      #pragma unroll
      for (int e = 0; e < 8; e++) kr[c8*8+e] = bf2f((unsigned short)dk[e]);
    }
    float mbk = mb[kk];
    float p[2];
    #pragma unroll
    for (int s = 0; s < 2; s++){
      int qj = t + s*192;
      float sc = mbk + tri[((size_t)qj*JDIM + kk)*4 + h];
      #pragma unroll
      for (int d = 0; d < 32; d++) sc = fmaf(qv[s][d], kr[d], sc);
      // scores are O(1); clamp keeps exp finite even for fully-masked rows
      sc = fminf(fmaxf(sc, -60.f), 60.f);
      p[s] = __expf(sc);
      l_[s] += p[s];
    }
    float vr[32];
    #pragma unroll
    for (int c8 = 0; c8 < 4; c8++){
      short8 dv = *(const short8*)(Vs + kk*DHD + c8*8);
      #pragma unroll
      for (int e = 0; e < 8; e++) vr[c8*8+e] = bf2f((unsigned short)dv[e]);
    }
    #pragma unroll
    for (int s = 0; s < 2; s++)
      #pragma unroll
      for (int d = 0; d < 32; d++) acc[s][d] = fmaf(p[s], vr[d], acc[s][d]);
  }

  #pragma unroll
  for (int s = 0; s < 2; s++){
    int qj = t + s*192;
    float rl = 1.0f / l_[s];
    size_t ro = (rbase + qj)*CDIM + h*DHD;
    #pragma unroll
    for (int c8 = 0; c8 < 4; c8++){
      short8 gd = *(const short8*)(gb + ro + c8*8);
      short8 ov;
      #pragma unroll
      for (int e = 0; e < 8; e++){
        float o = acc[s][c8*8+e] * rl * bf2f((unsigned short)gd[e]);
        ov[e] = (short)f2bf(o);
      }
      *(short8*)(og + ro + c8*8) = ov;
    }
  }
}

extern "C" void kernel_launch(void* const* d_in, const int* in_sizes, int n_in,
                              void* d_out, int out_size, void* d_ws, size_t ws_size,
                              hipStream_t stream)
{
  const float* x    = (const float*)d_in[0];
  const float* mask = (const float*)d_in[1];
  const float* lnw  = (const float*)d_in[2];
  const float* lnb  = (const float*)d_in[3];
  const float* wtri = (const float*)d_in[4];
  const float* wq   = (const float*)d_in[5];
  const float* wk   = (const float*)d_in[6];
  const float* wv   = (const float*)d_in[7];
  const float* wg   = (const float*)d_in[8];
  const float* bg   = (const float*)d_in[9];
  const float* wo   = (const float*)d_in[10];
  const float* bo   = (const float*)d_in[11];

  char* ws = (char*)d_ws;
  const size_t SZ = (size_t)NPOS * CDIM * 2;     // 37,748,736 B per [N,128] bf16
  ushort_t* xn  = (ushort_t*)(ws);
  ushort_t* qb  = (ushort_t*)(ws + 1*SZ);
  ushort_t* kbp = (ushort_t*)(ws + 2*SZ);
  ushort_t* vbp = (ushort_t*)(ws + 3*SZ);
  ushort_t* gbp = (ushort_t*)(ws + 4*SZ);
  ushort_t* og  = (ushort_t*)(ws + 5*SZ);
  ushort_t* wt  = (ushort_t*)(ws + 6*SZ);        // 5 * 128*128 bf16
  float*    tri = (float*)(ws + 6*SZ + 5*16384*2);

  ln_tri_kernel<<<NPOS/4, 256, 0, stream>>>(x, lnw, lnb, wtri, xn, tri);
  wt_kernel<<<320, 256, 0, stream>>>(wq, wk, wv, wg, wo, wt);
  proj_gemm_kernel<<<dim3(NPOS/128, 4), 256, 0, stream>>>(xn, wt, qb, bg);
  attn_kernel<<<dim3(JDIM, HNUM), 192, 0, stream>>>(qb, kbp, vbp, gbp, mask, tri, og);
  out_gemm_kernel<<<NPOS/128, 256, 0, stream>>>(og, wt + 4*16384, (float*)d_out, bo);
}

// Round 3
// 375.132 us; speedup vs baseline: 3.2921x; 3.2921x over previous
//
#include <hip/hip_runtime.h>
#include <hip/hip_bf16.h>

#define NPOS (384*384)
#define JDIM 384
#define CDIM 128
#define HNUM 4
#define DHD  32

typedef __attribute__((ext_vector_type(8))) short short8;
typedef __attribute__((ext_vector_type(4))) float floatx4;
typedef unsigned short ushort_t;

__device__ __forceinline__ float bf2f(unsigned short u){
  unsigned int x = ((unsigned int)u) << 16;
  return __builtin_bit_cast(float, x);
}
__device__ __forceinline__ unsigned short f2bf(float f){
  unsigned int u = __builtin_bit_cast(unsigned int, f);
  u = u + 0x7FFFu + ((u >> 16) & 1u);   // round-nearest-even
  return (unsigned short)(u >> 16);
}
// RNE-round two fp32 to bf16 and pack into one u32 (lo=a, hi=b)
__device__ __forceinline__ unsigned int pack2bf(float a, float b){
  unsigned int ua = __builtin_bit_cast(unsigned int, a);
  unsigned int ub = __builtin_bit_cast(unsigned int, b);
  ua = ua + 0x7FFFu + ((ua >> 16) & 1u);
  ub = ub + 0x7FFFu + ((ub >> 16) & 1u);
  return __builtin_amdgcn_perm(ub, ua, 0x07060302);  // [a.hi16, b.hi16]
}

// ---------------- LayerNorm + triangle bias (planar tri [h][pos]) ----------------
__global__ __launch_bounds__(256) void ln_tri_kernel(
    const float* __restrict__ x, const float* __restrict__ lnw,
    const float* __restrict__ lnb, const float* __restrict__ wtri,
    ushort_t* __restrict__ xn, float* __restrict__ trip)
{
  int wave = threadIdx.x >> 6, lane = threadIdx.x & 63;
  int pos = blockIdx.x * 4 + wave;
  const float2 xv = *(const float2*)(x + (size_t)pos*CDIM + lane*2);
  float x0 = xv.x, x1 = xv.y;
  float s = x0 + x1, ss = x0*x0 + x1*x1;
  #pragma unroll
  for (int o = 32; o > 0; o >>= 1){ s += __shfl_xor(s, o); ss += __shfl_xor(ss, o); }
  float mu  = s * (1.0f/128.0f);
  float var = ss * (1.0f/128.0f) - mu*mu;
  float rstd = rsqrtf(var + 1e-5f);
  float2 w2 = *(const float2*)(lnw + lane*2);
  float2 b2 = *(const float2*)(lnb + lane*2);
  float n0 = (x0 - mu)*rstd*w2.x + b2.x;
  float n1 = (x1 - mu)*rstd*w2.y + b2.y;
  ushort2 o2; o2.x = f2bf(n0); o2.y = f2bf(n1);
  *(ushort2*)(xn + (size_t)pos*CDIM + lane*2) = o2;
  float4 wt0 = *(const float4*)(wtri + lane*8);      // row c0 of [128,4]
  float4 wt1 = *(const float4*)(wtri + lane*8 + 4);  // row c1
  float t0 = n0*wt0.x + n1*wt1.x;
  float t1 = n0*wt0.y + n1*wt1.y;
  float t2 = n0*wt0.z + n1*wt1.z;
  float t3 = n0*wt0.w + n1*wt1.w;
  #pragma unroll
  for (int o = 32; o > 0; o >>= 1){
    t0 += __shfl_xor(t0, o); t1 += __shfl_xor(t1, o);
    t2 += __shfl_xor(t2, o); t3 += __shfl_xor(t3, o);
  }
  if (lane == 0){
    trip[0*NPOS + pos] = t0;
    trip[1*NPOS + pos] = t1;
    trip[2*NPOS + pos] = t2;
    trip[3*NPOS + pos] = t3;
  }
}

// ---------------- weight transpose + cast: W[c][f] fp32 -> Wt[f][c] bf16 ----------------
__global__ __launch_bounds__(256) void wt_kernel(
    const float* wq, const float* wk, const float* wv,
    const float* wg, const float* wo, ushort_t* __restrict__ wt)
{
  int mat = blockIdx.x >> 6;
  int idx = ((blockIdx.x & 63) << 8) | threadIdx.x;
  const float* src = (mat==0)?wq:(mat==1)?wk:(mat==2)?wv:(mat==3)?wg:wo;
  int f = idx >> 7, c = idx & 127;
  wt[mat*16384 + idx] = f2bf(src[c*128 + f]);
}

// ---------------- 128x128x128 MFMA GEMM tile ----------------
__device__ __forceinline__ void gemm_body(
    const ushort_t* __restrict__ A, const ushort_t* __restrict__ W,
    void* __restrict__ outv, const float* __restrict__ bias,
    int mode, int row0, ushort_t* As, ushort_t* Bs)
{
  int t = threadIdx.x;
  #pragma unroll
  for (int i = 0; i < 8; i++){
    int v = t + i*256;
    int row = v >> 4, c8 = v & 15;
    *(short8*)(As + row*144 + c8*8) = *(const short8*)(A + (size_t)(row0+row)*CDIM + c8*8);
    *(short8*)(Bs + row*144 + c8*8) = *(const short8*)(W + v*8);
  }
  __syncthreads();
  int w = t >> 6, lane = t & 63;
  int wm = (w & 1) * 64, wn = (w >> 1) * 64;
  int m = lane & 15, q4 = lane >> 4;
  floatx4 acc[4][4];
  #pragma unroll
  for (int mi = 0; mi < 4; mi++)
    #pragma unroll
    for (int ni = 0; ni < 4; ni++)
      acc[mi][ni] = (floatx4){0.f, 0.f, 0.f, 0.f};
  #pragma unroll
  for (int k0 = 0; k0 < 128; k0 += 32){
    int koff = k0 + q4*8;
    short8 af[4], bf[4];
    #pragma unroll
    for (int mi = 0; mi < 4; mi++) af[mi] = *(const short8*)(As + (wm + mi*16 + m)*144 + koff);
    #pragma unroll
    for (int ni = 0; ni < 4; ni++) bf[ni] = *(const short8*)(Bs + (wn + ni*16 + m)*144 + koff);
    #pragma unroll
    for (int mi = 0; mi < 4; mi++)
      #pragma unroll
      for (int ni = 0; ni < 4; ni++)
        acc[mi][ni] = __builtin_amdgcn_mfma_f32_16x16x32_bf16(af[mi], bf[ni], acc[mi][ni], 0, 0, 0);
  }
  const float scale = 0.17677669529663687f;  // 1/sqrt(32)
  #pragma unroll
  for (int mi = 0; mi < 4; mi++){
    #pragma unroll
    for (int ni = 0; ni < 4; ni++){
      int col = wn + ni*16 + m;
      float bv = (mode >= 2) ? bias[col] : 0.f;
      #pragma unroll
      for (int r = 0; r < 4; r++){
        float val = acc[mi][ni][r];
        if (mode == 1) val *= scale;
        else if (mode == 2) val = 1.f / (1.f + __expf(-(val + bv)));
        else if (mode == 3) val += bv;
        int row = wm + mi*16 + q4*4 + r;
        size_t oidx = (size_t)(row0+row)*CDIM + col;
        if (mode == 3) ((float*)outv)[oidx] = val;
        else           ((ushort_t*)outv)[oidx] = f2bf(val);
      }
    }
  }
}

__global__ __launch_bounds__(256) void proj_gemm_kernel(
    const ushort_t* __restrict__ xn, const ushort_t* __restrict__ wt,
    ushort_t* __restrict__ outb, const float* __restrict__ bg)
{
  __shared__ __align__(16) ushort_t As[128*144];
  __shared__ __align__(16) ushort_t Bs[128*144];
  int proj = blockIdx.y;                       // 0=q 1=k 2=v 3=g
  int mode = (proj == 0) ? 1 : (proj == 3) ? 2 : 0;
  gemm_body(xn, wt + proj*16384, outb + (size_t)proj*NPOS*CDIM, bg, mode,
            blockIdx.x * 128, As, Bs);
}

__global__ __launch_bounds__(256) void out_gemm_kernel(
    const ushort_t* __restrict__ og, const ushort_t* __restrict__ wt,
    float* __restrict__ out, const float* __restrict__ bo)
{
  __shared__ __align__(16) ushort_t As[128*144];
  __shared__ __align__(16) ushort_t Bs[128*144];
  gemm_body(og, wt, (void*)out, bo, 3, blockIdx.x * 128, As, Bs);
}

// ---------------- MFMA attention per (i,h) ----------------
// 256 threads = 4 waves; wave w owns Q-rows [w*96, w*96+96).
// K [384][32] bf16 LDS; Vt [32][384] bf16 LDS (j-permuted, padded stride 392);
// P wave-private [96][32] bf16 (stride 40), same j-permutation.
#define VT_STRIDE 392
#define P_STRIDE  40
__global__ __launch_bounds__(256, 2) void attn_kernel(
    const ushort_t* __restrict__ qb, const ushort_t* __restrict__ kb,
    const ushort_t* __restrict__ vb, const ushort_t* __restrict__ gb,
    const float* __restrict__ mask, const float* __restrict__ trip,
    ushort_t* __restrict__ og)
{
  __shared__ __align__(16) ushort_t Ks[JDIM*32];          // 24576 B
  __shared__ __align__(16) ushort_t Vt[32*VT_STRIDE];     // 25088 B
  __shared__ __align__(16) ushort_t Pb[4*96*P_STRIDE];    // 30720 B
  int i = blockIdx.x, h = blockIdx.y;
  int t = threadIdx.x;
  size_t rbase = (size_t)i * JDIM;

  // stage K natural, V transposed with within-block32 column permutation
  // actual col j = blk*32 + sub*16 + m  ->  stored pos blk*32 + m*2 + sub
  for (int idx = t; idx < JDIM*4; idx += 256){
    int j = idx >> 2, c8 = idx & 3;
    *(short8*)(Ks + j*32 + c8*8) = *(const short8*)(kb + (rbase + j)*CDIM + h*DHD + c8*8);
    short8 v8 = *(const short8*)(vb + (rbase + j)*CDIM + h*DHD + c8*8);
    int jb = j & 31;
    int jp = (j & ~31) | (((jb & 15) << 1) | (jb >> 4));
    #pragma unroll
    for (int e = 0; e < 8; e++) Vt[(c8*8 + e)*VT_STRIDE + jp] = (unsigned short)v8[e];
  }
  __syncthreads();

  int w = t >> 6, lane = t & 63;
  int m = lane & 15, q4 = lane >> 4;
  int wm = w * 96;
  ushort_t* Pw = Pb + w * 96 * P_STRIDE;

  // Q fragments (6 tiles of 16 rows), A-layout: lane m = row, k = q4*8..+8
  short8 qf[6];
  #pragma unroll
  for (int t6 = 0; t6 < 6; t6++)
    qf[t6] = *(const short8*)(qb + (rbase + wm + t6*16 + m)*CDIM + h*DHD + q4*8);

  floatx4 oacc[6][2];
  float lpart[6][4];
  #pragma unroll
  for (int t6 = 0; t6 < 6; t6++){
    oacc[t6][0] = (floatx4){0.f,0.f,0.f,0.f};
    oacc[t6][1] = (floatx4){0.f,0.f,0.f,0.f};
    #pragma unroll
    for (int r = 0; r < 4; r++) lpart[t6][r] = 0.f;
  }

  const float* triph = trip + (size_t)h * NPOS;

  for (int kbk = 0; kbk < 12; kbk++){
    int col0 = kbk * 32;
    // B-fragments of K (lane m = key column)
    short8 kf0 = *(const short8*)(Ks + (col0 + m)*32 + q4*8);
    short8 kf1 = *(const short8*)(Ks + (col0 + 16 + m)*32 + q4*8);
    float mb0 = 1e9f * (mask[rbase + col0 + m] - 1.0f);
    float mb1 = 1e9f * (mask[rbase + col0 + 16 + m] - 1.0f);

    #pragma unroll
    for (int t6 = 0; t6 < 6; t6++){
      floatx4 z = (floatx4){0.f,0.f,0.f,0.f};
      floatx4 s0 = __builtin_amdgcn_mfma_f32_16x16x32_bf16(qf[t6], kf0, z, 0, 0, 0);
      floatx4 s1 = __builtin_amdgcn_mfma_f32_16x16x32_bf16(qf[t6], kf1, z, 0, 0, 0);
      int qrow = wm + t6*16 + q4*4;
      #pragma unroll
      for (int r = 0; r < 4; r++){
        const float* trow = triph + (size_t)(qrow + r)*JDIM + col0;
        float sc0 = s0[r] + mb0 + trow[m];
        float sc1 = s1[r] + mb1 + trow[16 + m];
        float p0 = __expf(sc0);
        float p1 = __expf(sc1);
        lpart[t6][r] += p0 + p1;
        // store cols (m, m+16) packed at permuted pos m*2, m*2+1
        *(unsigned int*)(Pw + (t6*16 + q4*4 + r)*P_STRIDE + m*2) = pack2bf(p0, p1);
      }
    }
    // PV: A = P (permuted k), B = Vt (same permutation)
    short8 vf0 = *(const short8*)(Vt + m*VT_STRIDE + col0 + q4*8);
    short8 vf1 = *(const short8*)(Vt + (16 + m)*VT_STRIDE + col0 + q4*8);
    #pragma unroll
    for (int t6 = 0; t6 < 6; t6++){
      short8 pf = *(const short8*)(Pw + (t6*16 + m)*P_STRIDE + q4*8);
      oacc[t6][0] = __builtin_amdgcn_mfma_f32_16x16x32_bf16(pf, vf0, oacc[t6][0], 0, 0, 0);
      oacc[t6][1] = __builtin_amdgcn_mfma_f32_16x16x32_bf16(pf, vf1, oacc[t6][1], 0, 0, 0);
    }
  }

  // reduce l across the 16 m-lanes (same q4 group holds same rows)
  #pragma unroll
  for (int t6 = 0; t6 < 6; t6++)
    #pragma unroll
    for (int r = 0; r < 4; r++){
      float l = lpart[t6][r];
      l += __shfl_xor(l, 1); l += __shfl_xor(l, 2);
      l += __shfl_xor(l, 4); l += __shfl_xor(l, 8);
      lpart[t6][r] = 1.0f / (l + 1e-30f);
    }

  // epilogue: o = acc * (1/l) * g
  #pragma unroll
  for (int t6 = 0; t6 < 6; t6++){
    int qrow = wm + t6*16 + q4*4;
    #pragma unroll
    for (int dt = 0; dt < 2; dt++){
      #pragma unroll
      for (int r = 0; r < 4; r++){
        size_t oidx = (rbase + qrow + r)*CDIM + h*DHD + dt*16 + m;
        float o = oacc[t6][dt][r] * lpart[t6][r] * bf2f(gb[oidx]);
        og[oidx] = f2bf(o);
      }
    }
  }
}

extern "C" void kernel_launch(void* const* d_in, const int* in_sizes, int n_in,
                              void* d_out, int out_size, void* d_ws, size_t ws_size,
                              hipStream_t stream)
{
  const float* x    = (const float*)d_in[0];
  const float* mask = (const float*)d_in[1];
  const float* lnw  = (const float*)d_in[2];
  const float* lnb  = (const float*)d_in[3];
  const float* wtri = (const float*)d_in[4];
  const float* wq   = (const float*)d_in[5];
  const float* wk   = (const float*)d_in[6];
  const float* wv   = (const float*)d_in[7];
  const float* wg   = (const float*)d_in[8];
  const float* bg   = (const float*)d_in[9];
  const float* wo   = (const float*)d_in[10];
  const float* bo   = (const float*)d_in[11];

  char* ws = (char*)d_ws;
  const size_t SZ = (size_t)NPOS * CDIM * 2;     // 37,748,736 B per [N,128] bf16
  ushort_t* xn  = (ushort_t*)(ws);
  ushort_t* qb  = (ushort_t*)(ws + 1*SZ);
  ushort_t* kbp = (ushort_t*)(ws + 2*SZ);
  ushort_t* vbp = (ushort_t*)(ws + 3*SZ);
  ushort_t* gbp = (ushort_t*)(ws + 4*SZ);
  ushort_t* og  = (ushort_t*)(ws + 5*SZ);
  ushort_t* wt  = (ushort_t*)(ws + 6*SZ);        // 5 * 128*128 bf16
  float*    tri = (float*)(ws + 6*SZ + 5*16384*2);

  ln_tri_kernel<<<NPOS/4, 256, 0, stream>>>(x, lnw, lnb, wtri, xn, tri);
  wt_kernel<<<320, 256, 0, stream>>>(wq, wk, wv, wg, wo, wt);
  proj_gemm_kernel<<<dim3(NPOS/128, 4), 256, 0, stream>>>(xn, wt, qb, bg);
  attn_kernel<<<dim3(JDIM, HNUM), 256, 0, stream>>>(qb, kbp, vbp, gbp, mask, tri, og);
  out_gemm_kernel<<<NPOS/128, 256, 0, stream>>>(og, wt + 4*16384, (float*)d_out, bo);
}